// Round 6
// baseline (133.383 us; speedup 1.0000x reference)
//
#include <hip/hip_runtime.h>
#include <hip/hip_fp16.h>
#include <stdint.h>

// ---------------------------------------------------------------------------
// ThreeBodyLayer fused kernel v12 (MI355X / gfx950)
//
// All-f16 MFMA pipeline, log2-domain softplus. Scale algebra: W1/b1 carry
// log2(e); W2 carries ln2*log2(e)=1; b2*L2E; W3*LN2.
//
// v12 vs v11 (45us, VALU 44%, VGPR=32, ~55% issue-idle at ANY occupancy/
// block shape -> per-wave serialization from register starvation):
//  - amdgpu_waves_per_eu(4,8): VGPR cap 64 -> 128 so in-flight loads can
//    stay live (phase-2 steady-state needs ~84 regs for a 2-deep pipeline).
//  - Phase-2 hand-unrolled into a 2-deep software pipeline with NAMED load
//    sets (macro-stamped inline; no helper-fn refs -> no v8 scratch trap),
//    sched_barrier(0) at seams so the scheduler can't re-sink prefetches.
//    Next unit's 4 ds_read_b128 are in flight during current unit's
//    trans chain + MFMA + sp2 epilogue (~300+ cy of cover).
//  - Phase-1: all 8 W1-frag L2 loads per job hoisted ahead of the MFMA/
//    store chain (v11 issued them just-in-time -> serialized L2 latency).
//  - Keep v11 skeleton: no W1 LDS staging (frag-ordered ws image, L2
//    broadcast), 16-batch/8-wave blocks, 26.8KB LDS, ONE barrier,
//    operand-swapped phase-1 + packed b64 C-writes, b1/b2-in-C-init,
//    du-hoist, T chunk-swizzle, RNE converts, ws prep (fill is sunk cost).
// ---------------------------------------------------------------------------

typedef __attribute__((ext_vector_type(8))) _Float16 f16x8;
typedef __attribute__((ext_vector_type(2))) __fp16   fp16v2;   // cvt_pkrtz ret
typedef __attribute__((ext_vector_type(4))) float    f32x4;
typedef __attribute__((ext_vector_type(4))) unsigned int u32x4;

constexpr int   BPB       = 16;       // batch elems per block
constexpr int   NT        = 512;      // 8 waves
constexpr int   T_STRIDE  = 1664;     // 13 rows * 128 B, chunk-swizzled
constexpr int   Y_OFF     = BPB * T_STRIDE;       // 26624
constexpr int   LDS_BYTES = Y_OFF + 128;          // 26752

// d_ws layout (bytes)
constexpr int   WS_W1F   = 0;         // 24576: f16 W1 in MFMA frag order
constexpr int   WS_W2T   = 24576;     //  4096: f16 [m=32][k=64]
constexpr int   WS_B1    = 28672;     //   256: f32 b1*L2E
constexpr int   WS_B2    = 28928;     //   128: f32 b2*L2E
constexpr int   WS_W3    = 29056;     //   128: f32 W3*LN2

constexpr float L2E = 1.4426950408889634f;
constexpr float LN2 = 0.6931471805599453f;

// PAIRS i/j packed 3 bits per pair (15 pairs)
constexpr unsigned long long I_BITS =
  (0ull<<0)|(0ull<<3)|(0ull<<6)|(0ull<<9)|(0ull<<12)|
  (1ull<<15)|(1ull<<18)|(1ull<<21)|(1ull<<24)|
  (2ull<<27)|(2ull<<30)|(2ull<<33)|
  (3ull<<36)|(3ull<<39)|(4ull<<42);
constexpr unsigned long long J_BITS =
  (1ull<<0)|(2ull<<3)|(3ull<<6)|(4ull<<9)|(5ull<<12)|
  (2ull<<15)|(3ull<<18)|(4ull<<21)|(5ull<<24)|
  (3ull<<27)|(4ull<<30)|(5ull<<33)|
  (4ull<<36)|(5ull<<39)|(5ull<<42);

__device__ __forceinline__ float sp2(float s) {       // log2(1+exp2(s))
  float t = __builtin_amdgcn_exp2f(s);
  return __builtin_amdgcn_logf(1.0f + t);             // v_log_f32 = log2
}

__device__ __forceinline__ __half2 h1pair(__half2 u, __half2 a, __half2 b,
                                          __half2 one2) {
  __half2 s = __hadd2(__hadd2(u, a), b);
  __half2 t = h2exp2(s);                              // |s|<~8 -> safe in f16
  return h2log2(__hadd2(one2, t));
}

// ------------------------- prep: weights -> d_ws ---------------------------
__global__ __launch_bounds__(256)
void prep(const float* __restrict__ W1, const float* __restrict__ b1,
          const float* __restrict__ W2, const float* __restrict__ b2,
          const float* __restrict__ W3, char* __restrict__ ws)
{
  const int t = (int)(blockIdx.x * blockDim.x + threadIdx.x);   // 0..14591
  if (t < 12288) {
    // W1F frag image, element t = sl*4096 + nt*1024 + ks*512 + qd*128 + ln*8 + e
    // value = W1[dg][n]*L2E with dg = sl*64+ks*32+qd*8+e, n = nt*16+ln.
    const int e  = t & 7;
    const int ln = (t >> 3) & 15;
    const int qd = (t >> 7) & 3;
    const int ks = (t >> 9) & 1;
    const int nt = (t >> 10) & 3;
    const int sl = t >> 12;
    const int dg = sl * 64 + ks * 32 + qd * 8 + e;
    const int n  = nt * 16 + ln;
    ((uint16_t*)(ws + WS_W1F))[t] =
        __half_as_ushort(__float2half(W1[(size_t)dg * 64 + n] * L2E));
  } else if (t < 14336) {
    const int e = t - 12288;                          // W2 is [k=64][m=32]
    const int k = e >> 5, m = e & 31;
    *(uint16_t*)(ws + WS_W2T + (m * 64 + k) * 2) =
        __half_as_ushort(__float2half(W2[e]));
  } else if (t < 14400) {
    ((float*)(ws + WS_B1))[t - 14336] = b1[t - 14336] * L2E;
  } else if (t < 14432) {
    ((float*)(ws + WS_B2))[t - 14400] = b2[t - 14400] * L2E;
  } else if (t < 14464) {
    ((float*)(ws + WS_W3))[t - 14432] = W3[t - 14432] * LN2;
  }
}

// ---------------- phase-1 job macros (fully inline, named vars) ------------
#define P1_NT(T_, NTI, WA, WB, XA, XB)                                       \
  {                                                                          \
    f32x4 c_;                                                                \
    if ((T_) == 0) c_ = *(const f32x4*)(ws + WS_B1 + ((NTI)*16 + qd*4) * 4); \
    else           c_ = (f32x4){0.f, 0.f, 0.f, 0.f};                         \
    c_ = __builtin_amdgcn_mfma_f32_16x16x32_f16(WA, XA, c_, 0, 0, 0);        \
    c_ = __builtin_amdgcn_mfma_f32_16x16x32_f16(WB, XB, c_, 0, 0, 0);        \
    union PK_ { uint2 u; __half2 h[2]; } pk_;                                \
    pk_.h[0] = __halves2half2(__float2half(c_[0]), __float2half(c_[1]));     \
    pk_.h[1] = __halves2half2(__float2half(c_[2]), __float2half(c_[3]));     \
    *(uint2*)(smem + (size_t)ln * T_STRIDE + (T_) * 128                      \
              + (((((NTI) << 1) + (qd >> 1)) ^ swz) << 4) + (qd & 1) * 8) =  \
        pk_.u;                                                               \
  }

#define P1_JOB(T_, XA, XB)                                                   \
  {                                                                          \
    const int sl_ = ((T_) == 0) ? 0 : (((T_) <= 6) ? 1 : 2);                 \
    const char* wb_ = ws + WS_W1F + (size_t)(sl_*4096 + qd*128 + ln*8) * 2;  \
    const f16x8 W00_ = *(const f16x8*)(wb_ + 0);                             \
    const f16x8 W01_ = *(const f16x8*)(wb_ + 1024);                          \
    const f16x8 W10_ = *(const f16x8*)(wb_ + 2048);                          \
    const f16x8 W11_ = *(const f16x8*)(wb_ + 3072);                          \
    const f16x8 W20_ = *(const f16x8*)(wb_ + 4096);                          \
    const f16x8 W21_ = *(const f16x8*)(wb_ + 5120);                          \
    const f16x8 W30_ = *(const f16x8*)(wb_ + 6144);                          \
    const f16x8 W31_ = *(const f16x8*)(wb_ + 7168);                          \
    P1_NT(T_, 0, W00_, W01_, XA, XB)                                         \
    P1_NT(T_, 1, W10_, W11_, XA, XB)                                         \
    P1_NT(T_, 2, W20_, W21_, XA, XB)                                         \
    P1_NT(T_, 3, W30_, W31_, XA, XB)                                         \
  }

// ---------------- phase-2 unit macros (named pipeline sets) ----------------
#define PAIR_ADDR(Q_, TA_, TB_)                                              \
  {                                                                          \
    const int p_  = (Q_) >> 1;                                               \
    const int iv_ = (int)((I_BITS >> (3 * p_)) & 7ull);                      \
    const int jv_ = (int)((J_BITS >> (3 * p_)) & 7ull);                      \
    const int An_ = ((Q_) & 1) ? jv_ : iv_;                                  \
    const int Bn_ = ((Q_) & 1) ? iv_ : jv_;                                  \
    TA_ = Tb + (1 + An_) * 128;                                              \
    TB_ = Tb + (7 + Bn_) * 128;                                              \
  }

#define UNIT_LOAD(TA_, TB_, a0_, b0_, a1_, b1_)                              \
  a0_.u = *(const u32x4*)((TA_) + k0);                                       \
  b0_.u = *(const u32x4*)((TB_) + k0);                                       \
  a1_.u = *(const u32x4*)((TA_) + k1);                                       \
  b1_.u = *(const u32x4*)((TB_) + k1);

#define UNIT_COMP(a0_, b0_, a1_, b1_)                                        \
  {                                                                          \
    union AH_ { f16x8 v; __half2 h[4]; } A0_, A1_;                           \
    A0_.h[0] = h1pair(du0.h[0], a0_.h[0], b0_.h[0], one2);                   \
    A0_.h[1] = h1pair(du0.h[1], a0_.h[1], b0_.h[1], one2);                   \
    A0_.h[2] = h1pair(du0.h[2], a0_.h[2], b0_.h[2], one2);                   \
    A0_.h[3] = h1pair(du0.h[3], a0_.h[3], b0_.h[3], one2);                   \
    A1_.h[0] = h1pair(du1.h[0], a1_.h[0], b1_.h[0], one2);                   \
    A1_.h[1] = h1pair(du1.h[1], a1_.h[1], b1_.h[1], one2);                   \
    A1_.h[2] = h1pair(du1.h[2], a1_.h[2], b1_.h[2], one2);                   \
    A1_.h[3] = h1pair(du1.h[3], a1_.h[3], b1_.h[3], one2);                   \
    f32x4 c0_ = {b2v0, b2v0, b2v0, b2v0};                                    \
    f32x4 c1_ = {b2v1, b2v1, b2v1, b2v1};                                    \
    c0_ = __builtin_amdgcn_mfma_f32_16x16x32_f16(A0_.v, W2f[0][0], c0_, 0, 0, 0); \
    c0_ = __builtin_amdgcn_mfma_f32_16x16x32_f16(A1_.v, W2f[0][1], c0_, 0, 0, 0); \
    c1_ = __builtin_amdgcn_mfma_f32_16x16x32_f16(A0_.v, W2f[1][0], c1_, 0, 0, 0); \
    c1_ = __builtin_amdgcn_mfma_f32_16x16x32_f16(A1_.v, W2f[1][1], c1_, 0, 0, 0); \
    yacc0 += sp2(c0_[0]) * w3v0 + sp2(c1_[0]) * w3v1;                        \
    yacc1 += sp2(c0_[1]) * w3v0 + sp2(c1_[1]) * w3v1;                        \
    yacc2 += sp2(c0_[2]) * w3v0 + sp2(c1_[2]) * w3v1;                        \
    yacc3 += sp2(c0_[3]) * w3v0 + sp2(c1_[3]) * w3v1;                        \
  }

// ------------------------------ main kernel --------------------------------
__global__ __launch_bounds__(NT)
__attribute__((amdgpu_waves_per_eu(4, 8)))
void tb_fused(const float* __restrict__ core, const float* __restrict__ ligs,
              const char* __restrict__ ws,   const float* __restrict__ b3,
              float* __restrict__ out)
{
  extern __shared__ char smem[];
  const int tid  = (int)threadIdx.x;
  const int lane = tid & 63;
  const int ln   = lane & 15;        // fragment column
  const int qd   = lane >> 4;        // fragment quad
  const int swz  = ln & 7;           // XOR chunk swizzle key
  const int wv   = __builtin_amdgcn_readfirstlane(tid >> 6);  // 0..7
  const int b0   = (int)blockIdx.x * BPB;

  float* yred = (float*)(smem + Y_OFF);

  // ---- Phase-1 job table: 13 T-rows (0=core, 1..6=slab1, 7..12=slab2) ----
  const int t1 = wv;
  const int t2 = wv + 8;
  const bool j2 = (wv < 5);

  // x-tile global prefetch (cold HBM): issue first.
  float4 fA[2][4];
  {
    const int xr = (t1 == 0) ? 0 : (t1 <= 6 ? t1 : t1 - 6);
    const float* src = (xr == 0)
        ? (core + (size_t)(b0 + ln) * 64)
        : (ligs + ((size_t)(b0 + ln) * 6 + (size_t)(xr - 1)) * 64);
    #pragma unroll
    for (int ks = 0; ks < 2; ++ks) {
      fA[0][ks * 2 + 0] = *(const float4*)(src + ks * 32 + qd * 8);
      fA[0][ks * 2 + 1] = *(const float4*)(src + ks * 32 + qd * 8 + 4);
    }
  }
  if (j2) {
    const int xr = t2 - 6;                            // 2..6, slab 2
    const float* src = ligs + ((size_t)(b0 + ln) * 6 + (size_t)(xr - 1)) * 64;
    #pragma unroll
    for (int ks = 0; ks < 2; ++ks) {
      fA[1][ks * 2 + 0] = *(const float4*)(src + ks * 32 + qd * 8);
      fA[1][ks * 2 + 1] = *(const float4*)(src + ks * 32 + qd * 8 + 4);
    }
  }
  if (tid < BPB) yred[tid] = 0.0f;

  // Convert x tiles to f16 frags (B operand).
  union AFr { f16x8 v; fp16v2 p[4]; } Xf0[2], Xf1[2];
  #pragma unroll
  for (int ks = 0; ks < 2; ++ks) {
    Xf0[ks].p[0] = __builtin_amdgcn_cvt_pkrtz(fA[0][ks*2].x, fA[0][ks*2].y);
    Xf0[ks].p[1] = __builtin_amdgcn_cvt_pkrtz(fA[0][ks*2].z, fA[0][ks*2].w);
    Xf0[ks].p[2] = __builtin_amdgcn_cvt_pkrtz(fA[0][ks*2+1].x, fA[0][ks*2+1].y);
    Xf0[ks].p[3] = __builtin_amdgcn_cvt_pkrtz(fA[0][ks*2+1].z, fA[0][ks*2+1].w);
  }
  if (j2) {
    #pragma unroll
    for (int ks = 0; ks < 2; ++ks) {
      Xf1[ks].p[0] = __builtin_amdgcn_cvt_pkrtz(fA[1][ks*2].x, fA[1][ks*2].y);
      Xf1[ks].p[1] = __builtin_amdgcn_cvt_pkrtz(fA[1][ks*2].z, fA[1][ks*2].w);
      Xf1[ks].p[2] = __builtin_amdgcn_cvt_pkrtz(fA[1][ks*2+1].x, fA[1][ks*2+1].y);
      Xf1[ks].p[3] = __builtin_amdgcn_cvt_pkrtz(fA[1][ks*2+1].z, fA[1][ks*2+1].w);
    }
  }

  // ------------- Phase 1: up to 2 T-row jobs per wave, W1 frags from L2 ---
  P1_JOB(t1, Xf0[0].v, Xf0[1].v)
  if (j2) P1_JOB(t2, Xf1[0].v, Xf1[1].v)

  // W2 B-frags + epilogue consts from ws (pre-converted, L2-hot).
  f16x8 W2f[2][2];
  #pragma unroll
  for (int nt = 0; nt < 2; ++nt)
    #pragma unroll
    for (int ks = 0; ks < 2; ++ks)
      W2f[nt][ks] = *(const f16x8*)(ws + WS_W2T
          + ((nt * 16 + ln) * 64 + ks * 32 + qd * 8) * 2);
  const float b2v0 = ((const float*)(ws + WS_B2))[ln];
  const float b2v1 = ((const float*)(ws + WS_B2))[16 + ln];
  const float w3v0 = ((const float*)(ws + WS_W3))[ln];
  const float w3v1 = ((const float*)(ws + WS_W3))[16 + ln];

  __syncthreads();                                    // the ONLY barrier

  // ------------- Phase 2: 30 q-units over 8 waves, 2-deep pipeline --------
  const int qr = wv;                                  // 0..7
  const __half2 one2 = __float2half2_rn(1.0f);
  const char* Tb = smem + (size_t)ln * T_STRIDE;
  const int k0 = ((qd)     ^ swz) << 4;               // chunk qd   (ks=0)
  const int k1 = ((qd + 4) ^ swz) << 4;               // chunk qd+4 (ks=1)

  union U4 { u32x4 u; __half2 h[4]; };

  // Row 0 (core pre-activations) is unit-invariant: hoist its 2 reads.
  U4 du0, du1;
  du0.u = *(const u32x4*)(Tb + k0);
  du1.u = *(const u32x4*)(Tb + k1);

  float yacc0 = 0.f, yacc1 = 0.f, yacc2 = 0.f, yacc3 = 0.f;

  const char *TA0, *TB0, *TA1, *TB1, *TA2, *TB2, *TA3, *TB3;
  PAIR_ADDR(qr,      TA0, TB0)
  PAIR_ADDR(qr + 8,  TA1, TB1)
  PAIR_ADDR(qr + 16, TA2, TB2)
  const bool has3 = (qr < 6);                         // wave-uniform

  U4 Pa0, Pb0, Pa1, Pb1;                              // pipeline set P
  U4 Qa0, Qb0, Qa1, Qb1;                              // pipeline set Q

  UNIT_LOAD(TA0, TB0, Pa0, Pb0, Pa1, Pb1)             // load q0
  UNIT_LOAD(TA1, TB1, Qa0, Qb0, Qa1, Qb1)             // load q1
  __builtin_amdgcn_sched_barrier(0);
  UNIT_COMP(Pa0, Pb0, Pa1, Pb1)                       // comp q0
  __builtin_amdgcn_sched_barrier(0);
  UNIT_LOAD(TA2, TB2, Pa0, Pb0, Pa1, Pb1)             // load q2
  __builtin_amdgcn_sched_barrier(0);
  UNIT_COMP(Qa0, Qb0, Qa1, Qb1)                       // comp q1
  __builtin_amdgcn_sched_barrier(0);
  if (has3) {
    PAIR_ADDR(qr + 24, TA3, TB3)
    UNIT_LOAD(TA3, TB3, Qa0, Qb0, Qa1, Qb1)           // load q3
  }
  __builtin_amdgcn_sched_barrier(0);
  UNIT_COMP(Pa0, Pb0, Pa1, Pb1)                       // comp q2
  __builtin_amdgcn_sched_barrier(0);
  if (has3) {
    UNIT_COMP(Qa0, Qb0, Qa1, Qb1)                     // comp q3
  }

  // reduce over the 16 fragment columns (ln) inside each quad group
  float v0 = yacc0, v1 = yacc1, v2 = yacc2, v3 = yacc3;
  v0 += __shfl_xor(v0, 1); v1 += __shfl_xor(v1, 1);
  v2 += __shfl_xor(v2, 1); v3 += __shfl_xor(v3, 1);
  v0 += __shfl_xor(v0, 2); v1 += __shfl_xor(v1, 2);
  v2 += __shfl_xor(v2, 2); v3 += __shfl_xor(v3, 2);
  v0 += __shfl_xor(v0, 4); v1 += __shfl_xor(v1, 4);
  v2 += __shfl_xor(v2, 4); v3 += __shfl_xor(v3, 4);
  v0 += __shfl_xor(v0, 8); v1 += __shfl_xor(v1, 8);
  v2 += __shfl_xor(v2, 8); v3 += __shfl_xor(v3, 8);
  if (ln == 0) {
    atomicAdd(&yred[qd * 4 + 0], v0);
    atomicAdd(&yred[qd * 4 + 1], v1);
    atomicAdd(&yred[qd * 4 + 2], v2);
    atomicAdd(&yred[qd * 4 + 3], v3);
  }
  __syncthreads();
  if (tid < BPB) out[b0 + tid] = 0.5f * yred[tid] + 15.0f * b3[0];
}

extern "C" void kernel_launch(void* const* d_in, const int* in_sizes, int n_in,
                              void* d_out, int out_size, void* d_ws, size_t ws_size,
                              hipStream_t stream) {
  const float* core = (const float*)d_in[0];
  const float* ligs = (const float*)d_in[1];
  const float* W1   = (const float*)d_in[2];
  const float* b1   = (const float*)d_in[3];
  const float* W2   = (const float*)d_in[4];
  const float* b2   = (const float*)d_in[5];
  const float* W3   = (const float*)d_in[6];
  const float* b3   = (const float*)d_in[7];
  float* out = (float*)d_out;
  char*  ws  = (char*)d_ws;                 // 29 KB used; fill is sunk cost

  const int B = in_sizes[0] / 64;           // 32768
  const int grid = B / BPB;                 // 2048

  prep<<<dim3(57), dim3(256), 0, stream>>>(W1, b1, W2, b2, W3, ws);

  (void)hipFuncSetAttribute((const void*)tb_fused,
                            hipFuncAttributeMaxDynamicSharedMemorySize, LDS_BYTES);
  tb_fused<<<dim3(grid), dim3(NT), LDS_BYTES, stream>>>(
      core, ligs, ws, b3, out);
}